// Round 2
// baseline (201.419 us; speedup 1.0000x reference)
//
#include <hip/hip_runtime.h>
#include <math.h>

// Problem constants (B=8, N=M=4096, 3-D points, fp32)
#define BATCH   8
#define NPTS    4096
#define TOTAL   (BATCH * NPTS)        // 32768 points per array
#define THREADS 256
#define CHUNKS  8                     // M-split: 2*128*8 = 2048 blocks (8/CU)
#define CHUNK   (NPTS / CHUNKS)       // 512 q-points per block
#define PBLOCKS (TOTAL / THREADS)     // 128 point-blocks per direction
#define PB_PER_BATCH (NPTS / THREADS) // 16
#define NBLOCK  (2 * PBLOCKS * CHUNKS) // 2048

typedef float v2f __attribute__((ext_vector_type(2)));

// ws layout (16-byte aligned base):
//   [0, 16)                   : counter (uint, init 0 by pack)
//   [16, 16+8*TOTAL*4)        : packed SoA: [set][coord][TOTAL] floats,
//                               coord order X=-2x, Y=-2y, Z=-2z, W=||p||^2
//   [.., +2*TOTAL*4)          : dist min-accumulators (uint bits of f32, init +inf)

__global__ __launch_bounds__(THREADS)
void pack_kernel(const float* __restrict__ a1, const float* __restrict__ a2,
                 float* __restrict__ packed, unsigned* __restrict__ dist,
                 unsigned* __restrict__ counter) {
    int i = blockIdx.x * THREADS + threadIdx.x;   // 0 .. 2*TOTAL-1
    int dir = (i >= TOTAL) ? 1 : 0;
    int j = i - dir * TOTAL;
    const float* __restrict__ src = dir ? a2 : a1;
    float x = src[3 * j + 0];
    float y = src[3 * j + 1];
    float z = src[3 * j + 2];
    float sq = fmaf(x, x, fmaf(y, y, z * z));
    float* __restrict__ base = packed + (size_t)dir * 4 * TOTAL;
    base[0 * TOTAL + j] = -2.0f * x;
    base[1 * TOTAL + j] = -2.0f * y;
    base[2 * TOTAL + j] = -2.0f * z;
    base[3 * TOTAL + j] = sq;
    dist[i] = 0x7f800000u;            // +inf bits (min accumulator)
    if (i == 0) *counter = 0u;
}

static __device__ __forceinline__ v2f vmin2(v2f a, v2f b) {
    return __builtin_elementwise_min(a, b);
}

// d(p1,p2) - sq1 = fma(-2x2, x1, fma(-2y2, y1, fma(-2z2, z1, sq2)))
// computed 2 q-points at a time with v_pk_fma_f32; sq1 folded in after the min
// (monotone rounding => identical to per-pair add). max(d,0) also commutes.
__global__ __launch_bounds__(THREADS, 8)
void chamfer_min_kernel(const float* __restrict__ packed,
                        unsigned* __restrict__ dist,
                        unsigned* __restrict__ counter,
                        float* __restrict__ out) {
    const int bid   = blockIdx.x;
    const int dir   = bid >> 10;          // / (PBLOCKS*CHUNKS)=1024
    const int r     = bid & 1023;
    const int pb    = r >> 3;             // / CHUNKS
    const int chunk = r & 7;
    const int batch = pb >> 4;            // / PB_PER_BATCH — all wave-uniform

    const float* __restrict__ self  = packed + (size_t)dir * 4 * TOTAL;
    const float* __restrict__ other = packed + (size_t)(dir ^ 1) * 4 * TOTAL;

    const int i = pb * THREADS + threadIdx.x;     // my point index (0..TOTAL-1)
    const float x1  = -0.5f * self[0 * TOTAL + i];
    const float y1  = -0.5f * self[1 * TOTAL + i];
    const float z1  = -0.5f * self[2 * TOTAL + i];
    const float sq1 = self[3 * TOTAL + i];
    const v2f x1d = {x1, x1};
    const v2f y1d = {y1, y1};
    const v2f z1d = {z1, z1};

    // block-uniform q pointers (scalar-load friendly), SoA packed pairs
    const int qoff = batch * NPTS + chunk * CHUNK;
    const v2f* __restrict__ qx = (const v2f*)(other + 0 * TOTAL + qoff);
    const v2f* __restrict__ qy = (const v2f*)(other + 1 * TOTAL + qoff);
    const v2f* __restrict__ qz = (const v2f*)(other + 2 * TOTAL + qoff);
    const v2f* __restrict__ qw = (const v2f*)(other + 3 * TOTAL + qoff);

    const v2f inf2 = {__builtin_inff(), __builtin_inff()};
    v2f m0 = inf2, m1 = inf2, m2 = inf2, m3 = inf2;
    for (int j = 0; j < CHUNK / 2; j += 4) {
        v2f d0 = __builtin_elementwise_fma(qz[j + 0], z1d, qw[j + 0]);
        v2f d1 = __builtin_elementwise_fma(qz[j + 1], z1d, qw[j + 1]);
        v2f d2 = __builtin_elementwise_fma(qz[j + 2], z1d, qw[j + 2]);
        v2f d3 = __builtin_elementwise_fma(qz[j + 3], z1d, qw[j + 3]);
        d0 = __builtin_elementwise_fma(qy[j + 0], y1d, d0);
        d1 = __builtin_elementwise_fma(qy[j + 1], y1d, d1);
        d2 = __builtin_elementwise_fma(qy[j + 2], y1d, d2);
        d3 = __builtin_elementwise_fma(qy[j + 3], y1d, d3);
        d0 = __builtin_elementwise_fma(qx[j + 0], x1d, d0);
        d1 = __builtin_elementwise_fma(qx[j + 1], x1d, d1);
        d2 = __builtin_elementwise_fma(qx[j + 2], x1d, d2);
        d3 = __builtin_elementwise_fma(qx[j + 3], x1d, d3);
        m0 = vmin2(m0, d0);
        m1 = vmin2(m1, d1);
        m2 = vmin2(m2, d2);
        m3 = vmin2(m3, d3);
    }
    v2f mm = vmin2(vmin2(m0, m1), vmin2(m2, m3));
    float dmin = fminf(mm.x, mm.y) + sq1;
    dmin = fmaxf(dmin, 0.0f);   // non-negative => uint-ordered atomicMin valid
    atomicMin(dist + dir * TOTAL + i, __float_as_uint(dmin));

    // ---- completion handshake + fused final mean (last block only) ----
    __shared__ int amLast;
    __threadfence();                          // release our atomicMins
    if (threadIdx.x == 0)
        amLast = (atomicAdd(counter, 1u) == NBLOCK - 1);
    __syncthreads();
    if (amLast) {
        __threadfence();                      // acquire side
        const unsigned long long* __restrict__ dv =
            (const unsigned long long*)dist;  // 2*TOTAL floats = TOTAL u64
        float s0 = 0.0f, s1 = 0.0f;
        for (int k = threadIdx.x; k < TOTAL; k += 2 * THREADS) {
            unsigned long long v0 = __hip_atomic_load(dv + k, __ATOMIC_RELAXED,
                                                      __HIP_MEMORY_SCOPE_AGENT);
            unsigned long long v1 = __hip_atomic_load(dv + k + THREADS, __ATOMIC_RELAXED,
                                                      __HIP_MEMORY_SCOPE_AGENT);
            s0 += __uint_as_float((unsigned)v0) + __uint_as_float((unsigned)(v0 >> 32));
            s1 += __uint_as_float((unsigned)v1) + __uint_as_float((unsigned)(v1 >> 32));
        }
        float s = s0 + s1;
        #pragma unroll
        for (int off = 32; off > 0; off >>= 1) s += __shfl_down(s, off, 64);
        __shared__ float wsum[4];
        if ((threadIdx.x & 63) == 0) wsum[threadIdx.x >> 6] = s;
        __syncthreads();
        if (threadIdx.x == 0)
            out[0] = (wsum[0] + wsum[1] + wsum[2] + wsum[3]) * (1.0f / (float)TOTAL);
    }
}

extern "C" void kernel_launch(void* const* d_in, const int* in_sizes, int n_in,
                              void* d_out, int out_size, void* d_ws, size_t ws_size,
                              hipStream_t stream) {
    const float* a1 = (const float*)d_in[0];
    const float* a2 = (const float*)d_in[1];
    float* out = (float*)d_out;

    char* ws = (char*)d_ws;
    unsigned* counter = (unsigned*)ws;
    float*    packed  = (float*)(ws + 16);
    unsigned* dist    = (unsigned*)(ws + 16 + (size_t)8 * TOTAL * sizeof(float));

    pack_kernel<<<(2 * TOTAL) / THREADS, THREADS, 0, stream>>>(a1, a2, packed, dist, counter);
    chamfer_min_kernel<<<NBLOCK, THREADS, 0, stream>>>(packed, dist, counter, out);
}

// Round 3
// 157.787 us; speedup vs baseline: 1.2765x; 1.2765x over previous
//
#include <hip/hip_runtime.h>
#include <math.h>

// Problem constants (B=8, N=M=4096, 3-D points, fp32)
#define BATCH   8
#define NPTS    4096
#define TOTAL   (BATCH * NPTS)        // 32768 points per array
#define THREADS 256
#define P       4                     // self points per thread (register blocking)
#define TILE    (THREADS * P)         // 1024 self points per block
#define TILES   (TOTAL / TILE)        // 32 self-tiles per direction
#define CHUNKS  16                    // q-split per batch
#define CHUNK   (NPTS / CHUNKS)       // 256 q points staged in LDS (== THREADS)
#define NBLOCK  (2 * TILES * CHUNKS)  // 1024 blocks (4/CU)

typedef float v2f __attribute__((ext_vector_type(2)));

// ws layout: [0,16) counter ; [16, 16 + 2*TOTAL*4) dist (f32-as-uint min accumulators)

__global__ __launch_bounds__(256)
void init_kernel(unsigned* __restrict__ dist, unsigned* __restrict__ counter) {
    int i = blockIdx.x * 256 + threadIdx.x;       // 0 .. 2*TOTAL/4 - 1
    ((uint4*)dist)[i] = make_uint4(0x7f800000u, 0x7f800000u, 0x7f800000u, 0x7f800000u);
    if (i == 0) *counter = 0u;
}

// d(s,q) = ||s||^2 + ||q||^2 - 2 s.q
//        = [ fma(-2qx, sx, fma(-2qy, sy, fma(-2qz, sz, ||q||^2))) ] + ||s||^2
// The bracket is minimized over q (2-wide packed), ||s||^2 folded in after the
// min (monotone rounding), clamp after that (also monotone).
__global__ __launch_bounds__(THREADS, 4)
void chamfer_kernel(const float* __restrict__ a1, const float* __restrict__ a2,
                    unsigned* __restrict__ dist, unsigned* __restrict__ counter,
                    float* __restrict__ out) {
    const int bid   = blockIdx.x;
    const int dir   = bid >> 9;           // / (TILES*CHUNKS)=512
    const int r     = bid & 511;
    const int tile  = r >> 4;             // 0..31
    const int chunk = r & 15;             // 0..15
    const int batch = tile >> 2;          // 4 tiles per batch (4096/1024)

    const float* __restrict__ sraw = dir ? a2 : a1;
    const float* __restrict__ qraw = dir ? a1 : a2;

    // ---- stage q chunk into LDS, SoA (-2x | -2y | -2z | ||q||^2) ----
    __shared__ float lqx[CHUNK], lqy[CHUNK], lqz[CHUNK], lqw[CHUNK];
    {
        int p = batch * NPTS + chunk * CHUNK + threadIdx.x;   // CHUNK == THREADS
        float gx = qraw[3 * p + 0];
        float gy = qraw[3 * p + 1];
        float gz = qraw[3 * p + 2];
        lqx[threadIdx.x] = -2.0f * gx;
        lqy[threadIdx.x] = -2.0f * gy;
        lqz[threadIdx.x] = -2.0f * gz;
        lqw[threadIdx.x] = fmaf(gx, gx, fmaf(gy, gy, gz * gz));
    }

    // ---- self-point coefficients (P per thread, coalesced by THREADS stride) ----
    v2f xd[P], yd[P], zd[P];
    float sq[P];
    #pragma unroll
    for (int k = 0; k < P; k++) {
        int si = tile * TILE + k * THREADS + threadIdx.x;
        float x = sraw[3 * si + 0];
        float y = sraw[3 * si + 1];
        float z = sraw[3 * si + 2];
        xd[k] = (v2f){x, x};
        yd[k] = (v2f){y, y};
        zd[k] = (v2f){z, z};
        sq[k] = fmaf(x, x, fmaf(y, y, z * z));
    }
    __syncthreads();

    // ---- main loop: 2 q-points per iteration (packed), P self points each ----
    const v2f* __restrict__ qx2 = (const v2f*)lqx;
    const v2f* __restrict__ qy2 = (const v2f*)lqy;
    const v2f* __restrict__ qz2 = (const v2f*)lqz;
    const v2f* __restrict__ qw2 = (const v2f*)lqw;

    const v2f inf2 = {__builtin_inff(), __builtin_inff()};
    v2f acc[P] = {inf2, inf2, inf2, inf2};
    #pragma unroll 2
    for (int j = 0; j < CHUNK / 2; j++) {
        v2f ax = qx2[j];   // all lanes same address -> LDS broadcast, no conflicts
        v2f ay = qy2[j];
        v2f az = qz2[j];
        v2f aw = qw2[j];
        #pragma unroll
        for (int k = 0; k < P; k++) {
            v2f d = __builtin_elementwise_fma(az, zd[k], aw);
            d = __builtin_elementwise_fma(ay, yd[k], d);
            d = __builtin_elementwise_fma(ax, xd[k], d);
            acc[k] = __builtin_elementwise_min(acc[k], d);
        }
    }

    #pragma unroll
    for (int k = 0; k < P; k++) {
        int si = tile * TILE + k * THREADS + threadIdx.x;
        float dmin = fminf(acc[k].x, acc[k].y) + sq[k];
        dmin = fmaxf(dmin, 0.0f);   // non-negative => uint-ordered atomicMin valid
        atomicMin(dist + dir * TOTAL + si, __float_as_uint(dmin));
    }

    // ---- completion handshake + fused final mean (last block only) ----
    __shared__ int amLast;
    __threadfence();                          // release our atomicMins
    if (threadIdx.x == 0)
        amLast = (atomicAdd(counter, 1u) == NBLOCK - 1);
    __syncthreads();
    if (amLast) {
        __threadfence();                      // acquire
        const unsigned long long* __restrict__ dv =
            (const unsigned long long*)dist;  // 2*TOTAL floats = TOTAL u64
        float s = 0.0f;
        for (int k = threadIdx.x; k < TOTAL; k += THREADS) {
            unsigned long long v = __hip_atomic_load(dv + k, __ATOMIC_RELAXED,
                                                     __HIP_MEMORY_SCOPE_AGENT);
            s += __uint_as_float((unsigned)v) + __uint_as_float((unsigned)(v >> 32));
        }
        #pragma unroll
        for (int off = 32; off > 0; off >>= 1) s += __shfl_down(s, off, 64);
        __shared__ float wsum[4];
        if ((threadIdx.x & 63) == 0) wsum[threadIdx.x >> 6] = s;
        __syncthreads();
        if (threadIdx.x == 0)
            out[0] = (wsum[0] + wsum[1] + wsum[2] + wsum[3]) * (1.0f / (float)TOTAL);
    }
}

extern "C" void kernel_launch(void* const* d_in, const int* in_sizes, int n_in,
                              void* d_out, int out_size, void* d_ws, size_t ws_size,
                              hipStream_t stream) {
    const float* a1 = (const float*)d_in[0];
    const float* a2 = (const float*)d_in[1];
    float* out = (float*)d_out;

    char* ws = (char*)d_ws;
    unsigned* counter = (unsigned*)ws;
    unsigned* dist    = (unsigned*)(ws + 16);

    init_kernel<<<(2 * TOTAL / 4) / 256, 256, 0, stream>>>(dist, counter);
    chamfer_kernel<<<NBLOCK, THREADS, 0, stream>>>(a1, a2, dist, counter, out);
}

// Round 4
// 80.404 us; speedup vs baseline: 2.5051x; 1.9624x over previous
//
#include <hip/hip_runtime.h>
#include <math.h>

// Problem constants (B=8, N=M=4096, 3-D points, fp32)
#define BATCH   8
#define NPTS    4096
#define TOTAL   (BATCH * NPTS)        // 32768 points per array
#define THREADS 256
#define P       4                     // self points per thread (register blocking)
#define TILE    (THREADS * P)         // 1024 self points per block
#define TILES   (TOTAL / TILE)        // 32 self-tiles per direction
#define CHUNKS  16                    // q-split per batch
#define CHUNK   (NPTS / CHUNKS)       // 256 q points staged in LDS per block
#define NBLOCK  (2 * TILES * CHUNKS)  // 1024 blocks (4/CU)

typedef float v2f __attribute__((ext_vector_type(2)));

// ws layout: [0, 2*TOTAL*4) dist — f32-bits-as-uint min accumulators.
// Initialized to 0xFFFFFFFF by hipMemsetAsync: as uint that's UINT_MAX, so
// the first atomicMin with any clamped (non-negative, < +inf) float wins.

// d(s,q) = ||s||^2 + ||q||^2 - 2 s.q
//        = [ fma(-2qx, sx, fma(-2qy, sy, fma(-2qz, sz, ||q||^2))) ] + ||s||^2
// Bracket minimized over q (2-wide packed fp32); ||s||^2 folded in after the
// min (monotone rounding), clamp after that (also monotone).
__global__ __launch_bounds__(THREADS)
void chamfer_kernel(const float* __restrict__ a1, const float* __restrict__ a2,
                    unsigned* __restrict__ dist) {
    const int bid   = blockIdx.x;
    const int dir   = bid >> 9;           // / (TILES*CHUNKS)=512
    const int r     = bid & 511;
    const int tile  = r >> 4;             // 0..31
    const int chunk = r & 15;             // 0..15
    const int batch = tile >> 2;          // 4 tiles (of 1024) per batch of 4096

    const float* __restrict__ sraw = dir ? a2 : a1;
    const float* __restrict__ qraw = dir ? a1 : a2;

    // ---- stage q chunk into LDS as packed pairs:
    //      lA[j] = (-2x_{2j}, -2x_{2j+1}, -2y_{2j}, -2y_{2j+1})
    //      lB[j] = (-2z_{2j}, -2z_{2j+1}, ||q_{2j}||^2, ||q_{2j+1}||^2)
    __shared__ float4 lA[CHUNK / 2];
    __shared__ float4 lB[CHUNK / 2];
    if (threadIdx.x < CHUNK / 2) {
        const int j = threadIdx.x;
        const int p = batch * NPTS + chunk * CHUNK + 2 * j;
        const float* __restrict__ g = qraw + 3 * p;
        float x0 = g[0], y0 = g[1], z0 = g[2];
        float x1 = g[3], y1 = g[4], z1 = g[5];
        lA[j] = make_float4(-2.0f * x0, -2.0f * x1, -2.0f * y0, -2.0f * y1);
        lB[j] = make_float4(-2.0f * z0, -2.0f * z1,
                            fmaf(x0, x0, fmaf(y0, y0, z0 * z0)),
                            fmaf(x1, x1, fmaf(y1, y1, z1 * z1)));
    }

    // ---- self-point coefficients (P per thread, coalesced across threads) ----
    v2f xd[P], yd[P], zd[P];
    float sq[P];
    #pragma unroll
    for (int k = 0; k < P; k++) {
        int si = tile * TILE + k * THREADS + threadIdx.x;
        float x = sraw[3 * si + 0];
        float y = sraw[3 * si + 1];
        float z = sraw[3 * si + 2];
        xd[k] = (v2f){x, x};
        yd[k] = (v2f){y, y};
        zd[k] = (v2f){z, z};
        sq[k] = fmaf(x, x, fmaf(y, y, z * z));
    }
    __syncthreads();

    // ---- main loop: 2 q-points per iter (v_pk_fma_f32), P self points each.
    //      2 ds_read_b128 + 16 packed VALU per iteration; LDS broadcast
    //      (all lanes same address) => conflict-free.
    const v2f inf2 = {__builtin_inff(), __builtin_inff()};
    v2f acc[P] = {inf2, inf2, inf2, inf2};
    #pragma unroll 2
    for (int j = 0; j < CHUNK / 2; j++) {
        float4 A = lA[j];
        float4 Bv = lB[j];
        v2f ax = {A.x, A.y};
        v2f ay = {A.z, A.w};
        v2f az = {Bv.x, Bv.y};
        v2f aw = {Bv.z, Bv.w};
        #pragma unroll
        for (int k = 0; k < P; k++) {
            v2f d = __builtin_elementwise_fma(az, zd[k], aw);
            d = __builtin_elementwise_fma(ay, yd[k], d);
            d = __builtin_elementwise_fma(ax, xd[k], d);
            acc[k] = __builtin_elementwise_min(acc[k], d);
        }
    }

    #pragma unroll
    for (int k = 0; k < P; k++) {
        int si = tile * TILE + k * THREADS + threadIdx.x;
        float dmin = fminf(acc[k].x, acc[k].y) + sq[k];
        dmin = fmaxf(dmin, 0.0f);   // non-negative => uint-ordered atomicMin valid
        atomicMin(dist + dir * TOTAL + si, __float_as_uint(dmin));
    }
    // no fence / handshake: end-of-kernel release + kernel boundary make the
    // atomicMin results visible to the reduce kernel's plain loads.
}

__global__ __launch_bounds__(1024)
void reduce_kernel(const float* __restrict__ dist, float* __restrict__ out) {
    // mean(dist1) + mean(dist2) = (sum of all 2*TOTAL mins) / TOTAL
    const float4* __restrict__ dv = (const float4*)dist;  // 16384 float4
    float s = 0.0f;
    #pragma unroll
    for (int i = 0; i < (2 * TOTAL / 4) / 1024; i++) {
        float4 v = dv[i * 1024 + threadIdx.x];
        s += (v.x + v.y) + (v.z + v.w);
    }
    #pragma unroll
    for (int off = 32; off > 0; off >>= 1) s += __shfl_down(s, off, 64);
    __shared__ float wsum[16];
    if ((threadIdx.x & 63) == 0) wsum[threadIdx.x >> 6] = s;
    __syncthreads();
    if (threadIdx.x < 16) {
        float v = wsum[threadIdx.x];
        #pragma unroll
        for (int off = 8; off > 0; off >>= 1) v += __shfl_down(v, off, 16);
        if (threadIdx.x == 0) out[0] = v * (1.0f / (float)TOTAL);
    }
}

extern "C" void kernel_launch(void* const* d_in, const int* in_sizes, int n_in,
                              void* d_out, int out_size, void* d_ws, size_t ws_size,
                              hipStream_t stream) {
    const float* a1 = (const float*)d_in[0];
    const float* a2 = (const float*)d_in[1];
    float* out = (float*)d_out;

    unsigned* dist = (unsigned*)d_ws;

    // 0xFF bytes == UINT_MAX per word -> valid atomicMin(uint) init, no init kernel
    hipMemsetAsync(dist, 0xFF, (size_t)2 * TOTAL * sizeof(unsigned), stream);
    chamfer_kernel<<<NBLOCK, THREADS, 0, stream>>>(a1, a2, dist);
    reduce_kernel<<<1, 1024, 0, stream>>>((const float*)dist, out);
}